// Round 12
// baseline (71.159 us; speedup 1.0000x reference)
//
#include <hip/hip_runtime.h>
#include <hip/hip_bf16.h>

// NonlocalBlock2D: B=2, C=64, IC=32, H=W=96, N=9216.
// o = Wo @ softmax(theta^T phi) @ g + bo + x  (all 1x1 convs == channel GEMMs)
//
// Round-12: attn reverted to round-10 EXACT (passed, best). r11's two
// simultaneous untested changes (dbuf + asm cvt_pk) broke correctness and
// can't be attributed -- both dropped. New: combine+out fused into one
// epilogue kernel with a proper grid (576 blocks; 8 thr/pixel; y exchanged
// via padded LDS), saving one launch + the Y round-trip + Qb aliasing.

#define B_   2
#define C_   64
#define IC_  32
#define N_   9216
#define LOG2E 1.44269504088896f

typedef __attribute__((ext_vector_type(4))) float  f32x4;
typedef __attribute__((ext_vector_type(8))) short  s16x8;
typedef __attribute__((ext_vector_type(4))) short  s16x4;

static __device__ __forceinline__ ushort f2bf(float f) {
  union { __hip_bfloat16 h; ushort u; } cv;
  cv.h = __float2bfloat16(f);
  return cv.u;
}

static __device__ __forceinline__ float bf2f(ushort u) {
  union { uint i; float f; } c;
  c.i = ((uint)u) << 16;
  return c.f;
}

static __device__ __forceinline__ f32x4 mfma32(s16x8 a, s16x8 b, f32x4 c) {
  return __builtin_amdgcn_mfma_f32_16x16x32_bf16(a, b, c, 0, 0, 0);
}

// ---------------------------------------------------------------------------
// Kernel 1: projections. theta*log2e->Q[B][N][32], phi->K[B][N][32],
// g->Vt[B][32][N] with keys PERMUTED within each 64-tile:
//   j=n&63, u=j>>5, r=j&31 -> pos = u*32 + (r&15)*2 + (r>>4)
// grid: 4 ic-groups x 72 n-blocks = 288 blocks, 256 thr. Thread: 8 ic, 1 n.
// ---------------------------------------------------------------------------
__global__ __launch_bounds__(256) void proj_kernel(
    const float* __restrict__ x,
    const float* __restrict__ Wg, const float* __restrict__ bg,
    const float* __restrict__ Wt, const float* __restrict__ bt,
    const float* __restrict__ Wp, const float* __restrict__ bp,
    ushort* __restrict__ Qb, ushort* __restrict__ Kb, ushort* __restrict__ Vt)
{
  const int grp = blockIdx.x / 72;          // 0..3 (wave-uniform)
  const int ic0 = grp * 8;
  const int bn  = (blockIdx.x % 72) * 256 + threadIdx.x;
  const int b   = bn / N_;
  const int n   = bn % N_;

  float ag[8], at_[8], ap[8];
#pragma unroll
  for (int j = 0; j < 8; ++j) { ag[j] = 0.f; at_[j] = 0.f; ap[j] = 0.f; }

  const float* xp = x + (size_t)b * C_ * N_ + n;
#pragma unroll 8
  for (int c = 0; c < C_; ++c) {
    const float xv = xp[(size_t)c * N_];
#pragma unroll
    for (int j = 0; j < 8; ++j) {
      ag[j]  = fmaf(Wg[(ic0 + j) * C_ + c], xv, ag[j]);
      at_[j] = fmaf(Wt[(ic0 + j) * C_ + c], xv, at_[j]);
      ap[j]  = fmaf(Wp[(ic0 + j) * C_ + c], xv, ap[j]);
    }
  }

  union { ushort u[8]; s16x8 v; } qv, kv;
#pragma unroll
  for (int j = 0; j < 8; ++j) {
    const int ic = ic0 + j;
    qv.u[j] = f2bf(LOG2E * (at_[j] + bt[ic]));   // theta, exp2 domain
    kv.u[j] = f2bf(ap[j] + bp[ic]);              // phi
  }
  *reinterpret_cast<s16x8*>(Qb + (size_t)bn * IC_ + ic0) = qv.v;
  *reinterpret_cast<s16x8*>(Kb + (size_t)bn * IC_ + ic0) = kv.v;

  // permuted key position for V
  const int j6 = n & 63, u = j6 >> 5, r = j6 & 31;
  const int nperm = (n - j6) + u * 32 + (r & 15) * 2 + (r >> 4);
#pragma unroll
  for (int j = 0; j < 8; ++j) {
    const int ic = ic0 + j;
    Vt[(size_t)(b * IC_ + ic) * N_ + nperm] = f2bf(ag[j] + bg[ic]);
  }
}

// ---------------------------------------------------------------------------
// Kernel 2: flash attention over ONE KV segment (N_/NSEG keys, tiles of 64).
// block = 4 waves x 64 queries = 256 q; wave holds FOUR Q-fragments so each
// K/V LDS tile read serves 4096 scores. Swapped QK^T: mfma(K,Q).
// p = exp2(S') directly (bounded; partials merge by summation).
// Key-halves (u=0,1) processed sequentially to bound register pressure.
// Denominator via ones-MFMA. LDS single-buffered, 2 barriers/tile.
// (ROUND-10 EXACT -- known-good.)
// ---------------------------------------------------------------------------
template<int NSEG>
__global__ __launch_bounds__(256, 4) void attn_kernel(
    const ushort* __restrict__ Qb, const ushort* __restrict__ Kb,
    const ushort* __restrict__ Vt, ushort* __restrict__ Opart,
    float* __restrict__ Lp)
{
  constexpr int NT = 144 / NSEG;           // 64-key tiles per segment
  constexpr int SKEYS = N_ / NSEG;
  constexpr int QBLK = N_ / 256;           // 36 q-blocks
  constexpr int KSTR = 36;                 // 72B rows
  constexpr int VSTR = 70;                 // 140B rows
  __shared__ __align__(16) ushort Kl[64 * KSTR];
  __shared__ __align__(16) ushort Vl[32 * VSTR];

  const int qblk = blockIdx.x % QBLK;
  const int bs   = blockIdx.x / QBLK;      // b*NSEG + seg
  const int seg  = bs % NSEG;
  const int b    = bs / NSEG;
  const int key0 = seg * SKEYS;

  const int tid  = threadIdx.x;
  const int lane = tid & 63;
  const int wave = tid >> 6;
  const int q16  = lane & 15;
  const int h    = lane >> 4;

  const int qbase = qblk * 256 + wave * 64;   // 4 frags: qbase + 16f

  const short ONE = (short)0x3F80;
  const s16x8 ones = {ONE, ONE, ONE, ONE, ONE, ONE, ONE, ONE};

  const ushort* qptr = Qb + (size_t)(b * N_ + qbase + q16) * IC_ + h * 8;
  const s16x8 qfA = *reinterpret_cast<const s16x8*>(qptr);
  const s16x8 qfB = *reinterpret_cast<const s16x8*>(qptr + 16 * IC_);
  const s16x8 qfC = *reinterpret_cast<const s16x8*>(qptr + 32 * IC_);
  const s16x8 qfD = *reinterpret_cast<const s16x8*>(qptr + 48 * IC_);

  f32x4 aA0 = {0.f,0.f,0.f,0.f}, aA1 = {0.f,0.f,0.f,0.f}, aLA = {0.f,0.f,0.f,0.f};
  f32x4 aB0 = {0.f,0.f,0.f,0.f}, aB1 = {0.f,0.f,0.f,0.f}, aLB = {0.f,0.f,0.f,0.f};
  f32x4 aC0 = {0.f,0.f,0.f,0.f}, aC1 = {0.f,0.f,0.f,0.f}, aLC = {0.f,0.f,0.f,0.f};
  f32x4 aD0 = {0.f,0.f,0.f,0.f}, aD1 = {0.f,0.f,0.f,0.f}, aLD = {0.f,0.f,0.f,0.f};

  // staging: K tile 4KB + V tile 4KB; 256 threads x 16B each.
  const int krow = tid >> 2, kpart = tid & 3;
  const ushort* kg = Kb + ((size_t)b * N_ + key0 + krow) * IC_ + kpart * 8;
  ushort* kl_dst = &Kl[krow * KSTR + kpart * 8];

  const int vd = tid >> 3, vpp = tid & 7;
  const ushort* vg = Vt + (size_t)(b * IC_ + vd) * N_ + key0 + vpp * 8;
  ushort* vl_dst = &Vl[vd * VSTR + vpp * 8];

  s16x8 kreg = *reinterpret_cast<const s16x8*>(kg);
  s16x8 vreg = *reinterpret_cast<const s16x8*>(vg);

  for (int it = 0; it < NT; ++it) {
    *reinterpret_cast<s16x8*>(kl_dst) = kreg;
    *reinterpret_cast<s16x8*>(vl_dst) = vreg;
    __syncthreads();

    if (it + 1 < NT) {
      kg += 64 * IC_;
      vg += 64;
      kreg = *reinterpret_cast<const s16x8*>(kg);
      vreg = *reinterpret_cast<const s16x8*>(vg);
    }

    // two key-halves sequentially (bounds VGPR: one kf/vf pair set live)
#pragma unroll
    for (int u = 0; u < 2; ++u) {
      const s16x8 kf0 = *reinterpret_cast<const s16x8*>(&Kl[(u * 32 + q16) * KSTR + h * 8]);
      const s16x8 kf1 = *reinterpret_cast<const s16x8*>(&Kl[(u * 32 + 16 + q16) * KSTR + h * 8]);
      const s16x8 vf0 = *reinterpret_cast<const s16x8*>(&Vl[q16 * VSTR + u * 32 + h * 8]);
      const s16x8 vf1 = *reinterpret_cast<const s16x8*>(&Vl[(16 + q16) * VSTR + u * 32 + h * 8]);
      const f32x4 z = {0.f, 0.f, 0.f, 0.f};

      // ---- qfrag A ----
      {
        __builtin_amdgcn_s_setprio(1);
        const f32x4 s0 = mfma32(kf0, qfA, z);
        const f32x4 s1 = mfma32(kf1, qfA, z);
        __builtin_amdgcn_s_setprio(0);
        union { ushort us[8]; s16x8 v; } pa;
#pragma unroll
        for (int i = 0; i < 4; ++i) {
          pa.us[2 * i]     = f2bf(__builtin_amdgcn_exp2f(s0[i]));
          pa.us[2 * i + 1] = f2bf(__builtin_amdgcn_exp2f(s1[i]));
        }
        __builtin_amdgcn_s_setprio(1);
        aA0 = mfma32(pa.v, vf0, aA0);
        aA1 = mfma32(pa.v, vf1, aA1);
        aLA = mfma32(pa.v, ones, aLA);
        __builtin_amdgcn_s_setprio(0);
      }
      // ---- qfrag B ----
      {
        __builtin_amdgcn_s_setprio(1);
        const f32x4 s0 = mfma32(kf0, qfB, z);
        const f32x4 s1 = mfma32(kf1, qfB, z);
        __builtin_amdgcn_s_setprio(0);
        union { ushort us[8]; s16x8 v; } pa;
#pragma unroll
        for (int i = 0; i < 4; ++i) {
          pa.us[2 * i]     = f2bf(__builtin_amdgcn_exp2f(s0[i]));
          pa.us[2 * i + 1] = f2bf(__builtin_amdgcn_exp2f(s1[i]));
        }
        __builtin_amdgcn_s_setprio(1);
        aB0 = mfma32(pa.v, vf0, aB0);
        aB1 = mfma32(pa.v, vf1, aB1);
        aLB = mfma32(pa.v, ones, aLB);
        __builtin_amdgcn_s_setprio(0);
      }
      // ---- qfrag C ----
      {
        __builtin_amdgcn_s_setprio(1);
        const f32x4 s0 = mfma32(kf0, qfC, z);
        const f32x4 s1 = mfma32(kf1, qfC, z);
        __builtin_amdgcn_s_setprio(0);
        union { ushort us[8]; s16x8 v; } pa;
#pragma unroll
        for (int i = 0; i < 4; ++i) {
          pa.us[2 * i]     = f2bf(__builtin_amdgcn_exp2f(s0[i]));
          pa.us[2 * i + 1] = f2bf(__builtin_amdgcn_exp2f(s1[i]));
        }
        __builtin_amdgcn_s_setprio(1);
        aC0 = mfma32(pa.v, vf0, aC0);
        aC1 = mfma32(pa.v, vf1, aC1);
        aLC = mfma32(pa.v, ones, aLC);
        __builtin_amdgcn_s_setprio(0);
      }
      // ---- qfrag D ----
      {
        __builtin_amdgcn_s_setprio(1);
        const f32x4 s0 = mfma32(kf0, qfD, z);
        const f32x4 s1 = mfma32(kf1, qfD, z);
        __builtin_amdgcn_s_setprio(0);
        union { ushort us[8]; s16x8 v; } pa;
#pragma unroll
        for (int i = 0; i < 4; ++i) {
          pa.us[2 * i]     = f2bf(__builtin_amdgcn_exp2f(s0[i]));
          pa.us[2 * i + 1] = f2bf(__builtin_amdgcn_exp2f(s1[i]));
        }
        __builtin_amdgcn_s_setprio(1);
        aD0 = mfma32(pa.v, vf0, aD0);
        aD1 = mfma32(pa.v, vf1, aD1);
        aLD = mfma32(pa.v, ones, aLD);
        __builtin_amdgcn_s_setprio(0);
      }
    }
    __syncthreads();
  }

  // store partial O (bf16, unnormalized) and partial l (from ones-MFMA)
  const size_t obase0 = ((size_t)(b * NSEG + seg) * N_);
#pragma unroll
  for (int r = 0; r < 4; ++r) {
    const int qA = qbase + h * 4 + r;
    Opart[(obase0 + qA) * IC_ + q16]           = f2bf(aA0[r]);
    Opart[(obase0 + qA) * IC_ + 16 + q16]      = f2bf(aA1[r]);
    Opart[(obase0 + qA + 16) * IC_ + q16]      = f2bf(aB0[r]);
    Opart[(obase0 + qA + 16) * IC_ + 16 + q16] = f2bf(aB1[r]);
    Opart[(obase0 + qA + 32) * IC_ + q16]      = f2bf(aC0[r]);
    Opart[(obase0 + qA + 32) * IC_ + 16 + q16] = f2bf(aC1[r]);
    Opart[(obase0 + qA + 48) * IC_ + q16]      = f2bf(aD0[r]);
    Opart[(obase0 + qA + 48) * IC_ + 16 + q16] = f2bf(aD1[r]);
  }
  if (q16 == 0) {
#pragma unroll
    for (int r = 0; r < 4; ++r) {
      Lp[obase0 + qbase + h * 4 + r]      = aLA[r];
      Lp[obase0 + qbase + 16 + h * 4 + r] = aLB[r];
      Lp[obase0 + qbase + 32 + h * 4 + r] = aLC[r];
      Lp[obase0 + qbase + 48 + h * 4 + r] = aLD[r];
    }
  }
}

// ---------------------------------------------------------------------------
// Kernel 3: fused epilogue. 32 pixels per block, 8 threads per pixel.
// Phase 1 (p=tid>>3, e=tid&7): y[e*4..e*4+3] = sum_s O_s / sum_s l_s,
// stored to padded LDS ylds[32][33] (bank-conflict-free).
// Phase 2 (pe=tid&31, g=tid>>5): out[oc=g*8+j] = Wo·y + bo + x, stores
// coalesced across the 32 consecutive pixels. grid 576 x 256.
// ---------------------------------------------------------------------------
template<int NSEG>
__global__ __launch_bounds__(256) void epilogue_kernel(
    const ushort* __restrict__ Opart, const float* __restrict__ Lp,
    const float* __restrict__ Wo, const float* __restrict__ bo,
    const float* __restrict__ x, float* __restrict__ out)
{
  __shared__ float ylds[32][33];

  const int tid = threadIdx.x;
  const int bn0 = blockIdx.x * 32;

  // ---- phase 1: segment reduction ----
  {
    const int p  = tid >> 3;        // pixel 0..31
    const int e  = tid & 7;         // dim-quarter 0..7 (4 dims)
    const int bn = bn0 + p;
    const int b  = bn / N_;
    const int q  = bn % N_;

    float l = 0.f;
    float o[4] = {0.f, 0.f, 0.f, 0.f};
#pragma unroll
    for (int s = 0; s < NSEG; ++s) {
      const size_t base = (size_t)(b * NSEG + s) * N_ + q;
      l += Lp[base];
      union { s16x4 v; ushort us[4]; } ov;
      ov.v = *reinterpret_cast<const s16x4*>(Opart + base * IC_ + e * 4);
#pragma unroll
      for (int j = 0; j < 4; ++j) o[j] += bf2f(ov.us[j]);
    }
    const float inv = 1.0f / l;
#pragma unroll
    for (int j = 0; j < 4; ++j) ylds[p][e * 4 + j] = o[j] * inv;
  }
  __syncthreads();

  // ---- phase 2: out-projection + residual ----
  {
    const int pe  = tid & 31;       // pixel 0..31 (consecutive lanes -> coalesced)
    const int g   = tid >> 5;       // oc group 0..7
    const int oc0 = g * 8;
    const int bn  = bn0 + pe;
    const int b   = bn / N_;
    const int n   = bn % N_;

    float acc[8];
#pragma unroll
    for (int j = 0; j < 8; ++j) acc[j] = bo[oc0 + j];

#pragma unroll
    for (int ic = 0; ic < IC_; ++ic) {
      const float yv = ylds[pe][ic];
#pragma unroll
      for (int j = 0; j < 8; ++j)
        acc[j] = fmaf(Wo[(oc0 + j) * IC_ + ic], yv, acc[j]);
    }

#pragma unroll
    for (int j = 0; j < 8; ++j) {
      const int oc = oc0 + j;
      const size_t xi = (size_t)(b * C_ + oc) * N_ + n;
      out[xi] = acc[j] + x[xi];
    }
  }
}

// ---------------------------------------------------------------------------
extern "C" void kernel_launch(void* const* d_in, const int* in_sizes, int n_in,
                              void* d_out, int out_size, void* d_ws, size_t ws_size,
                              hipStream_t stream)
{
  const float* x  = (const float*)d_in[0];
  const float* Wg = (const float*)d_in[1];
  const float* bg = (const float*)d_in[2];
  const float* Wt = (const float*)d_in[3];
  const float* bt = (const float*)d_in[4];
  const float* Wp = (const float*)d_in[5];
  const float* bp = (const float*)d_in[6];
  const float* Wo = (const float*)d_in[7];
  const float* bo = (const float*)d_in[8];
  float* out = (float*)d_out;

  char* ws = (char*)d_ws;
  const size_t szb = (size_t)B_ * N_ * IC_ * sizeof(ushort);   // 1,179,648 B
  ushort* Qb = (ushort*)(ws);                       // theta*log2e, bf16 [B][N][32]
  ushort* Kb = (ushort*)(ws + szb);                 // phi, bf16 [B][N][32]
  ushort* Vt = (ushort*)(ws + 2 * szb);             // g,   bf16 [B][32][N] (perm'd)
  ushort* Op = (ushort*)(ws + 3 * szb);             // partial O bf16 [B][S][N][32]

  const size_t need24 = 3 * szb + 24 * szb + (size_t)24 * B_ * N_ * sizeof(float);
  const size_t need16 = 3 * szb + 16 * szb + (size_t)16 * B_ * N_ * sizeof(float);
  const int epiblocks = (B_ * N_) / 32;   // 576

  proj_kernel<<<288, 256, 0, stream>>>(x, Wg, bg, Wt, bt, Wp, bp, Qb, Kb, Vt);
  if (ws_size >= need24) {
    float* Lp = (float*)(ws + 3 * szb + 24 * szb);
    attn_kernel<24><<<B_ * 24 * (N_ / 256), 256, 0, stream>>>(Qb, Kb, Vt, Op, Lp);
    epilogue_kernel<24><<<epiblocks, 256, 0, stream>>>(Op, Lp, Wo, bo, x, out);
  } else if (ws_size >= need16) {
    float* Lp = (float*)(ws + 3 * szb + 16 * szb);
    attn_kernel<16><<<B_ * 16 * (N_ / 256), 256, 0, stream>>>(Qb, Kb, Vt, Op, Lp);
    epilogue_kernel<16><<<epiblocks, 256, 0, stream>>>(Op, Lp, Wo, bo, x, out);
  } else {
    float* Lp = (float*)(ws + 3 * szb + 8 * szb);
    attn_kernel<8><<<B_ * 8 * (N_ / 256), 256, 0, stream>>>(Qb, Kb, Vt, Op, Lp);
    epilogue_kernel<8><<<epiblocks, 256, 0, stream>>>(Op, Lp, Wo, bo, x, out);
  }
}